// Round 1
// baseline (1017.630 us; speedup 1.0000x reference)
//
#include <hip/hip_runtime.h>
#include <math.h>

typedef long long I64;

// ---- problem constants (from setup_inputs) ----
#define NB    8
#define NTOK  576
#define DIM   1024
#define NMASK 64
#define HMASK 384
#define WMASK 384
#define QDIM  4096
#define HDIM  1024
#define KREG  32
#define CCTX  128
#define GH    24
#define GW    24
#define GNUM  576      // GH*GW

// ---- output layout (floats, concatenated in return order) ----
#define OFF_VIS 0
#define OFF_REG 1318912
#define OFF_CTX 1581056
#define OFF_BG  2629632
#define OFF_PP  2637824
#define OFF_RW  2642432
#define OFF_SEL 2647040
#define OFF_GV  2648064

// ---- workspace layout (floats) ----
#define WS_BS   0          // B*M*576 block sums
#define WS_NMAT 294912     // B*32*576 normalized masks
#define WS_SCK  442368     // B*32 scores_k
#define WS_H1   442624     // B*32*1024 silu hidden
#define WS_Q    704768     // B*1024 question row
#define WS_RS   712960     // B*576 routing scores
#define WS_GV   717568     // B grounding_valid
#define WS_FLAG 717576     // B*576 selected flag
#define WS_PP   722184     // B*576 patch prior
// total 726792 floats ~ 2.9 MB

// ======================== K1: mask 16x16 block sums ========================
// grid: B*M*24 (one block per 16-row band of one mask), 384 threads = 16 rows x 24 xblocks
__global__ __launch_bounds__(384) void k_blocksum(const float* __restrict__ masks,
                                                  float* __restrict__ bs) {
  int gid = blockIdx.x;
  int yband = gid % 24;
  int bm = gid / 24;
  const float4* src = (const float4*)(masks + (I64)bm * (HMASK * WMASK) + (I64)yband * 16 * WMASK);
  int row = threadIdx.x / 24;
  int xb  = threadIdx.x % 24;
  const float4* p = src + row * 96 + xb * 4;
  float s = 0.f;
  #pragma unroll
  for (int j = 0; j < 4; ++j) {
    float4 v = p[j];
    s += v.x; s += v.y; s += v.z; s += v.w;
  }
  __shared__ float sm[16][24];
  sm[row][xb] = s;
  __syncthreads();
  if (threadIdx.x < 24) {
    float tt = 0.f;
    #pragma unroll
    for (int r = 0; r < 16; ++r) tt += sm[r][threadIdx.x];
    bs[(I64)bm * GNUM + yband * 24 + threadIdx.x] = tt;
  }
}

// ======================== K2: per-batch small ops ========================
// grid: B, 256 threads. Sort scores, mg/nm/scores_k, patch_prior, geometry, silu-MLP hidden.
__global__ __launch_bounds__(256) void k_perbatch(
    const float* __restrict__ bs, const float* __restrict__ scores,
    const float* __restrict__ W1, const float* __restrict__ b1,
    float* __restrict__ ws, float* __restrict__ out) {
  int b = blockIdx.x;
  int t = threadIdx.x;
  __shared__ float s_sc[NMASK];
  __shared__ int   s_order[NMASK];
  __shared__ float s_sck[KREG];
  __shared__ int   s_midx[KREG];
  __shared__ int   s_valid[KREG];
  __shared__ float s_rowsum[KREG];
  __shared__ float s_pp[GNUM];
  __shared__ float s_geom[KREG][5];
  __shared__ float s_red[64];
  __shared__ int   s_gv;
  __shared__ float s_ppsum;

  if (t == 0) s_gv = 0;
  __syncthreads();
  // grounding_valid: any mask with positive total sum (uses ALL 64 masks)
  if (t < NMASK) {
    const float* p = bs + ((I64)b * NMASK + t) * GNUM;
    float s = 0.f;
    for (int n = 0; n < GNUM; ++n) s += p[n];
    if (s > 0.f) atomicOr(&s_gv, 1);
    s_sc[t] = scores[b * NMASK + t];
  }
  __syncthreads();
  const int gv = s_gv;
  // stable descending rank (matches argsort(-scores), ties -> lower index first)
  if (t < NMASK) {
    float v = s_sc[t];
    int r = 0;
    for (int j = 0; j < NMASK; ++j) {
      float vj = s_sc[j];
      r += (vj > v) || (vj == v && j < t);
    }
    s_order[r] = t;
  }
  __syncthreads();
  if (t < KREG) {
    int m = s_order[t];
    float sc = s_sc[m];
    int valid = (sc >= 0.5f) ? 1 : 0;
    s_midx[t] = m;
    s_valid[t] = valid;
    float sck = gv ? (valid ? sc : 0.f) : 1.f;
    s_sck[t] = sck;
    ws[WS_SCK + b * KREG + t] = sck;
  }
  __syncthreads();

  const float inv256 = 1.f / 256.f;
  const float invN = 1.f / 576.f;
  auto MG = [&](int k, int n) -> float {
    if (!gv) return invN;
    if (!s_valid[k]) return 0.f;
    return bs[((I64)b * NMASK + s_midx[k]) * GNUM + n] * inv256;
  };

  // row sums of max(mg,0): 8 lanes per k, butterfly within 8-lane group
  {
    int k = t >> 3, sub = t & 7;
    float part = 0.f;
    for (int n = sub; n < GNUM; n += 8) part += fmaxf(MG(k, n), 0.f);
    part += __shfl_xor(part, 1);
    part += __shfl_xor(part, 2);
    part += __shfl_xor(part, 4);
    if (sub == 0) s_rowsum[k] = part;
  }
  __syncthreads();
  // nm = max(mg,0) / max(rowsum, 1e-6)
  for (int idx = t; idx < KREG * GNUM; idx += 256) {
    int k = idx / GNUM, n = idx - k * GNUM;
    float v = fmaxf(MG(k, n), 0.f);
    ws[WS_NMAT + ((I64)b * KREG + k) * GNUM + n] = v / fmaxf(s_rowsum[k], 1e-6f);
  }
  // patch prior raw
  for (int n = t; n < GNUM; n += 256) {
    float raw = 0.f;
    for (int k = 0; k < KREG; ++k) raw += MG(k, n) * s_sck[k];
    s_pp[n] = fmaxf(raw, 0.f);
  }
  __syncthreads();
  if (t < 64) {
    float s = 0.f;
    for (int n = t; n < GNUM; n += 64) s += s_pp[n];
    s_red[t] = s;
  }
  __syncthreads();
  if (t == 0) {
    float s = 0.f;
    for (int i = 0; i < 64; ++i) s += s_red[i];
    s_ppsum = s;
  }
  __syncthreads();
  {
    float den = fmaxf(s_ppsum, 1e-6f);
    for (int n = t; n < GNUM; n += 256) {
      float v = gv ? (s_pp[n] / den) : invN;
      ws[WS_PP + b * GNUM + n] = v;
      out[OFF_PP + b * GNUM + n] = v;
    }
  }
  // geometry (one thread per region)
  if (t < KREG) {
    unsigned colmask = 0u;
    int ymin = GH, ymax = -1, cnt = 0;
    for (int y = 0; y < GH; ++y) {
      unsigned rowm = 0u;
      for (int x = 0; x < GW; ++x) {
        if (MG(t, y * GW + x) > 0.05f) rowm |= (1u << x);
      }
      if (rowm) { if (y < ymin) ymin = y; if (y > ymax) ymax = y; }
      colmask |= rowm;
      cnt += __popc(rowm);
    }
    float g0, g1, g2, g3, g4;
    if (cnt > 0) {
      int xmin = __ffs(colmask) - 1;
      int xmax = 31 - __clz(colmask);
      g0 = (float)xmin / 23.f;
      g1 = (float)ymin / 23.f;
      g2 = (float)xmax / 23.f;
      g3 = (float)ymax / 23.f;
      g4 = (float)cnt / 576.f;
    } else { g0 = g1 = g2 = g3 = g4 = 0.f; }
    s_geom[t][0] = g0; s_geom[t][1] = g1; s_geom[t][2] = g2; s_geom[t][3] = g3; s_geom[t][4] = g4;
  }
  __syncthreads();
  // hidden1 = silu(geom @ W1 + b1)
  for (int idx = t; idx < KREG * HDIM; idx += 256) {
    int k = idx >> 10, j = idx & 1023;
    float x = 0.f;
    #pragma unroll
    for (int i = 0; i < 5; ++i) x += s_geom[k][i] * W1[i * HDIM + j];
    x += b1[j];
    float sg = 1.f / (1.f + expf(-x));
    ws[WS_H1 + ((I64)b * KREG + k) * HDIM + j] = x * sg;
  }
  if (t == 0) {
    float g = gv ? 1.f : 0.f;
    ws[WS_GV + b] = g;
    out[OFF_GV + b] = g;
  }
}

// ======================== K3: q = question_embed @ Wq + bq ========================
// grid: (HDIM/16, B), 256 threads = 16 d-lanes x 16 i-groups
__global__ __launch_bounds__(256) void k_qrow(
    const float* __restrict__ qe, const float* __restrict__ Wq,
    const float* __restrict__ bq, float* __restrict__ ws) {
  int b = blockIdx.y;
  int dl = threadIdx.x & 15;
  int ig = threadIdx.x >> 4;
  int d = blockIdx.x * 16 + dl;
  float acc = 0.f;
  for (int i = ig; i < QDIM; i += 16)
    acc += qe[b * QDIM + i] * Wq[(I64)i * HDIM + d];
  __shared__ float s_part[16][16];
  s_part[ig][dl] = acc;
  __syncthreads();
  if (threadIdx.x < 16) {
    float s = 0.f;
    #pragma unroll
    for (int g = 0; g < 16; ++g) s += s_part[g][threadIdx.x];
    int dd = blockIdx.x * 16 + threadIdx.x;
    ws[WS_Q + (I64)b * HDIM + dd] = s + bq[dd];
  }
}

// ======================== K4: region tokens (pooled*score + g + te0) ========================
// grid: 128 = 8b * 4 kgroups * 4 dgroups, 256 threads (one d each)
__global__ __launch_bounds__(256) void k_region(
    const float* __restrict__ pt, const float* __restrict__ W2,
    const float* __restrict__ b2, const float* __restrict__ te,
    float* __restrict__ ws, float* __restrict__ out) {
  int blk = blockIdx.x;
  int b = blk >> 4, kg = (blk >> 2) & 3, dg = blk & 3;
  int d = dg * 256 + threadIdx.x;
  const float* nmb = ws + WS_NMAT + ((I64)b * KREG + kg * 8) * GNUM;
  const float* h1b = ws + WS_H1 + ((I64)b * KREG + kg * 8) * HDIM;
  float accP[8] = {0, 0, 0, 0, 0, 0, 0, 0};
  float accG[8] = {0, 0, 0, 0, 0, 0, 0, 0};
  for (int n = 0; n < GNUM; ++n) {
    float p = pt[((I64)b * NTOK + n) * DIM + d];
    #pragma unroll
    for (int kk = 0; kk < 8; ++kk)
      accP[kk] = fmaf(nmb[kk * GNUM + n], p, accP[kk]);
  }
  for (int j = 0; j < HDIM; ++j) {
    float wv = W2[(I64)j * DIM + d];
    #pragma unroll
    for (int kk = 0; kk < 8; ++kk)
      accG[kk] = fmaf(h1b[kk * HDIM + j], wv, accG[kk]);
  }
  float bb = b2[d], t0 = te[d];
  #pragma unroll
  for (int kk = 0; kk < 8; ++kk) {
    int k = kg * 8 + kk;
    float g = accG[kk] + bb;
    float val = accP[kk] * ws[WS_SCK + b * KREG + k] + g + t0;
    out[OFF_REG + ((I64)b * KREG + k) * DIM + d] = val;
    out[OFF_VIS + ((I64)b * 161 + k) * DIM + d] = val;
  }
}

// ======================== K5: fused hid GEMM + tanh + Wo dot -> routing scores ========================
// grid: 256 blocks (b x 32 token-tiles of 18), 256 threads = 128 d-lanes x 2 token-halves (9 each)
#define TOKT 18
#define TOKP 24
#define KC   64
#define NCH  16
__global__ __launch_bounds__(256) void k_hid(
    const float* __restrict__ pt, const float* __restrict__ Wv,
    const float* __restrict__ bv, const float* __restrict__ Wp,
    const float* __restrict__ bp, const float* __restrict__ Wo,
    const float* __restrict__ bo, float* __restrict__ ws) {
  int blk = blockIdx.x;
  int b = blk >> 5;
  int n0 = (blk & 31) * TOKT;
  int t = threadIdx.x;
  int th = t >> 7;
  int dl = t & 127;
  int d0 = dl * 8;
  __shared__ float smA[2][KC][TOKP];
  float acc[9][8];
  #pragma unroll
  for (int i = 0; i < 9; ++i)
    #pragma unroll
    for (int j = 0; j < 8; ++j) acc[i][j] = 0.f;

  int stok = t >> 4, skq = t & 15;
  int scol = (stok < 9) ? stok : stok + 3;
  int stok2 = 16 + (t >> 4), skq2 = t & 15;  // only t<32 uses
  int scol2 = stok2 + 3;

  const I64 rowbase = ((I64)b * NTOK + n0 + stok) * DIM;
  const I64 rowbase2 = ((I64)b * NTOK + n0 + ((t < 32) ? stok2 : 16)) * DIM;

  // prologue: stage chunk 0
  {
    float4 va = *(const float4*)&pt[rowbase + skq * 4];
    smA[0][skq * 4 + 0][scol] = va.x;
    smA[0][skq * 4 + 1][scol] = va.y;
    smA[0][skq * 4 + 2][scol] = va.z;
    smA[0][skq * 4 + 3][scol] = va.w;
    if (t < 32) {
      float4 vb = *(const float4*)&pt[rowbase2 + skq2 * 4];
      smA[0][skq2 * 4 + 0][scol2] = vb.x;
      smA[0][skq2 * 4 + 1][scol2] = vb.y;
      smA[0][skq2 * 4 + 2][scol2] = vb.z;
      smA[0][skq2 * 4 + 3][scol2] = vb.w;
    }
  }
  for (int c = 0; c < NCH; ++c) {
    __syncthreads();
    float4 na = {0, 0, 0, 0}, nb = {0, 0, 0, 0};
    if (c + 1 < NCH) {
      na = *(const float4*)&pt[rowbase + (c + 1) * KC + skq * 4];
      if (t < 32) nb = *(const float4*)&pt[rowbase2 + (c + 1) * KC + skq2 * 4];
    }
    int buf = c & 1;
    const float* wbase = Wv + (I64)c * KC * HDIM + d0;
    #pragma unroll 2
    for (int kk = 0; kk < KC; ++kk) {
      const float* arow = &smA[buf][kk][th * 12];
      float4 a0 = *(const float4*)(arow);
      float4 a1 = *(const float4*)(arow + 4);
      float a8 = arow[8];
      float4 w0 = *(const float4*)&wbase[kk * HDIM];
      float4 w1 = *(const float4*)&wbase[kk * HDIM + 4];
      float av[9] = {a0.x, a0.y, a0.z, a0.w, a1.x, a1.y, a1.z, a1.w, a8};
      float wv8[8] = {w0.x, w0.y, w0.z, w0.w, w1.x, w1.y, w1.z, w1.w};
      #pragma unroll
      for (int i = 0; i < 9; ++i)
        #pragma unroll
        for (int j = 0; j < 8; ++j)
          acc[i][j] = fmaf(av[i], wv8[j], acc[i][j]);
    }
    if (c + 1 < NCH) {
      int nbuf = (c + 1) & 1;
      smA[nbuf][skq * 4 + 0][scol] = na.x;
      smA[nbuf][skq * 4 + 1][scol] = na.y;
      smA[nbuf][skq * 4 + 2][scol] = na.z;
      smA[nbuf][skq * 4 + 3][scol] = na.w;
      if (t < 32) {
        smA[nbuf][skq2 * 4 + 0][scol2] = nb.x;
        smA[nbuf][skq2 * 4 + 1][scol2] = nb.y;
        smA[nbuf][skq2 * 4 + 2][scol2] = nb.z;
        smA[nbuf][skq2 * 4 + 3][scol2] = nb.w;
      }
    }
  }
  // epilogue: biases + tanh + Wo dot
  float bvv[8], bpv[8], wpv[8], wov[8], qv[8];
  {
    float4 x0 = *(const float4*)&bv[d0], x1 = *(const float4*)&bv[d0 + 4];
    bvv[0] = x0.x; bvv[1] = x0.y; bvv[2] = x0.z; bvv[3] = x0.w;
    bvv[4] = x1.x; bvv[5] = x1.y; bvv[6] = x1.z; bvv[7] = x1.w;
  }
  {
    float4 x0 = *(const float4*)&bp[d0], x1 = *(const float4*)&bp[d0 + 4];
    bpv[0] = x0.x; bpv[1] = x0.y; bpv[2] = x0.z; bpv[3] = x0.w;
    bpv[4] = x1.x; bpv[5] = x1.y; bpv[6] = x1.z; bpv[7] = x1.w;
  }
  {
    float4 x0 = *(const float4*)&Wp[d0], x1 = *(const float4*)&Wp[d0 + 4];
    wpv[0] = x0.x; wpv[1] = x0.y; wpv[2] = x0.z; wpv[3] = x0.w;
    wpv[4] = x1.x; wpv[5] = x1.y; wpv[6] = x1.z; wpv[7] = x1.w;
  }
  {
    float4 x0 = *(const float4*)&Wo[d0], x1 = *(const float4*)&Wo[d0 + 4];
    wov[0] = x0.x; wov[1] = x0.y; wov[2] = x0.z; wov[3] = x0.w;
    wov[4] = x1.x; wov[5] = x1.y; wov[6] = x1.z; wov[7] = x1.w;
  }
  {
    const float* q = ws + WS_Q + (I64)b * HDIM + d0;
    float4 x0 = *(const float4*)q, x1 = *(const float4*)(q + 4);
    qv[0] = x0.x; qv[1] = x0.y; qv[2] = x0.z; qv[3] = x0.w;
    qv[4] = x1.x; qv[5] = x1.y; qv[6] = x1.z; qv[7] = x1.w;
  }
  const float* ppb = ws + WS_PP + b * GNUM + n0 + th * 9;
  float partial[9];
  #pragma unroll
  for (int i = 0; i < 9; ++i) {
    float ppv = ppb[i];
    float s = 0.f;
    #pragma unroll
    for (int j = 0; j < 8; ++j) {
      float pre = acc[i][j] + bvv[j] + bpv[j] + qv[j] + ppv * wpv[j];
      s = fmaf(wov[j], tanhf(pre), s);
    }
    partial[i] = s;
  }
  #pragma unroll
  for (int i = 0; i < 9; ++i) {
    float p = partial[i];
    for (int off = 1; off < 64; off <<= 1) p += __shfl_xor(p, off);
    partial[i] = p;
  }
  __shared__ float s_red2[4][9];
  if ((t & 63) == 0) {
    #pragma unroll
    for (int i = 0; i < 9; ++i) s_red2[t >> 6][i] = partial[i];
  }
  __syncthreads();
  if (t < TOKT) {
    int hh = t / 9, ii = t - hh * 9;
    float r = s_red2[hh * 2][ii] + s_red2[hh * 2 + 1][ii] + bo[0];
    ws[WS_RS + b * NTOK + n0 + hh * 9 + ii] = r;
  }
}

// ======================== K6: softmax + stable top-k ========================
// grid: B, 576 threads
__global__ __launch_bounds__(576) void k_soft(float* __restrict__ ws, float* __restrict__ out) {
  int b = blockIdx.x, t = threadIdx.x;
  __shared__ float s_rs[NTOK];
  __shared__ float s_w[9];
  __shared__ float s_max, s_sum;
  s_rs[t] = ws[WS_RS + b * NTOK + t];
  __syncthreads();
  float v = s_rs[t];
  // stable descending rank (matches lax.top_k tie rule)
  int r = 0;
  for (int j = 0; j < NTOK; ++j) {
    float vj = s_rs[j];
    r += (vj > v) || (vj == v && j < t);
  }
  // max reduce
  float m = v;
  for (int off = 1; off < 64; off <<= 1) m = fmaxf(m, __shfl_xor(m, off));
  if ((t & 63) == 0) s_w[t >> 6] = m;
  __syncthreads();
  if (t == 0) {
    float mm = s_w[0];
    for (int i = 1; i < 9; ++i) mm = fmaxf(mm, s_w[i]);
    s_max = mm;
  }
  __syncthreads();
  float e = expf(v - s_max);
  float s = e;
  for (int off = 1; off < 64; off <<= 1) s += __shfl_xor(s, off);
  if ((t & 63) == 0) s_w[t >> 6] = s;
  __syncthreads();
  if (t == 0) {
    float ss = 0.f;
    for (int i = 0; i < 9; ++i) ss += s_w[i];
    s_sum = ss;
  }
  __syncthreads();
  out[OFF_RW + b * NTOK + t] = e / s_sum;
  int sel = (r < CCTX) ? 1 : 0;
  ws[WS_FLAG + b * NTOK + t] = sel ? 1.f : 0.f;
  if (sel) out[OFF_SEL + b * CCTX + r] = (float)t;
}

// ======================== K7: context gather ========================
// grid: (CCTX, B), 256 threads (float4 each)
__global__ __launch_bounds__(256) void k_ctx(const float* __restrict__ pt, const float* __restrict__ te,
                                             const float* __restrict__ outr, float* __restrict__ out) {
  int rr = blockIdx.x, b = blockIdx.y;
  int idx = (int)outr[OFF_SEL + b * CCTX + rr];
  int d = threadIdx.x * 4;
  float4 v = *(const float4*)&pt[((I64)b * NTOK + idx) * DIM + d];
  float4 e = *(const float4*)&te[DIM + d];
  v.x += e.x; v.y += e.y; v.z += e.z; v.w += e.w;
  *(float4*)&out[OFF_CTX + ((I64)b * CCTX + rr) * DIM + d] = v;
  *(float4*)&out[OFF_VIS + ((I64)b * 161 + KREG + rr) * DIM + d] = v;
}

// ======================== K8: background token ========================
// grid: B, 256 threads (float4 each)
__global__ __launch_bounds__(256) void k_bg(const float* __restrict__ pt, const float* __restrict__ te,
                                            const float* __restrict__ ws, float* __restrict__ out) {
  int b = blockIdx.x;
  int d = threadIdx.x * 4;
  const float r = 1.f / 448.f;   // residual sum is exactly 448 = 576-128
  float ax = 0.f, ay = 0.f, az = 0.f, aw = 0.f;
  for (int n = 0; n < NTOK; ++n) {
    if (ws[WS_FLAG + b * NTOK + n] == 0.f) {
      float4 v = *(const float4*)&pt[((I64)b * NTOK + n) * DIM + d];
      ax = fmaf(r, v.x, ax); ay = fmaf(r, v.y, ay);
      az = fmaf(r, v.z, az); aw = fmaf(r, v.w, aw);
    }
  }
  float4 e = *(const float4*)&te[2 * DIM + d];
  float4 o;
  o.x = ax + e.x; o.y = ay + e.y; o.z = az + e.z; o.w = aw + e.w;
  *(float4*)&out[OFF_BG + (I64)b * DIM + d] = o;
  *(float4*)&out[OFF_VIS + ((I64)b * 161 + 160) * DIM + d] = o;
}

// ======================== launcher ========================
extern "C" void kernel_launch(void* const* d_in, const int* in_sizes, int n_in,
                              void* d_out, int out_size, void* d_ws, size_t ws_size,
                              hipStream_t stream) {
  (void)in_sizes; (void)n_in; (void)out_size; (void)ws_size;
  const float* pt     = (const float*)d_in[0];
  const float* masks  = (const float*)d_in[1];
  const float* scores = (const float*)d_in[2];
  const float* qe     = (const float*)d_in[3];
  const float* W1     = (const float*)d_in[4];
  const float* b1     = (const float*)d_in[5];
  const float* W2     = (const float*)d_in[6];
  const float* b2     = (const float*)d_in[7];
  const float* Wv     = (const float*)d_in[8];
  const float* bv     = (const float*)d_in[9];
  const float* Wp     = (const float*)d_in[10];
  const float* bp     = (const float*)d_in[11];
  const float* Wq     = (const float*)d_in[12];
  const float* bq     = (const float*)d_in[13];
  const float* Wo     = (const float*)d_in[14];
  const float* bo     = (const float*)d_in[15];
  const float* te     = (const float*)d_in[16];
  float* out = (float*)d_out;
  float* ws  = (float*)d_ws;

  k_blocksum<<<dim3(NB * NMASK * 24), dim3(384), 0, stream>>>(masks, ws + WS_BS);
  k_perbatch<<<dim3(NB), dim3(256), 0, stream>>>(ws + WS_BS, scores, W1, b1, ws, out);
  k_qrow<<<dim3(HDIM / 16, NB), dim3(256), 0, stream>>>(qe, Wq, bq, ws);
  k_region<<<dim3(128), dim3(256), 0, stream>>>(pt, W2, b2, te, ws, out);
  k_hid<<<dim3(256), dim3(256), 0, stream>>>(pt, Wv, bv, Wp, bp, Wo, bo, ws);
  k_soft<<<dim3(NB), dim3(576), 0, stream>>>(ws, out);
  k_ctx<<<dim3(CCTX, NB), dim3(256), 0, stream>>>(pt, te, out, out);
  k_bg<<<dim3(NB), dim3(256), 0, stream>>>(pt, te, ws, out);
}

// Round 2
// 701.439 us; speedup vs baseline: 1.4508x; 1.4508x over previous
//
#include <hip/hip_runtime.h>
#include <math.h>

typedef long long I64;

// ---- problem constants ----
#define NB    8
#define NTOK  576
#define DIM   1024
#define NMASK 64
#define HMASK 384
#define WMASK 384
#define QDIM  4096
#define HDIM  1024
#define KREG  32
#define CCTX  128
#define GH    24
#define GW    24
#define GNUM  576

// ---- output layout (floats) ----
#define OFF_VIS 0
#define OFF_REG 1318912
#define OFF_CTX 1581056
#define OFF_BG  2629632
#define OFF_PP  2637824
#define OFF_RW  2642432
#define OFF_SEL 2647040
#define OFF_GV  2648064

// ---- workspace layout (floats) ----
#define WS_BS   0          // B*M*576 block sums
#define WS_NMAT 294912     // B*32*576 normalized masks
#define WS_SCK  442368     // B*32 scores_k
#define WS_H1   442624     // B*32*1024 silu hidden
#define WS_Q    704768     // B*1024 question row
#define WS_RS   712960     // B*576 routing scores
#define WS_GV   717568     // B grounding_valid
#define WS_FLAG 717576     // B*576 selected flag
#define WS_PP   722184     // B*576 patch prior
#define WS_RSP  726792     // B*576*8 routing score partials (per col-block)
// total 763656 floats ~ 3.05 MB

// ======================== K1: mask 16x16 block sums ========================
__global__ __launch_bounds__(384) void k_blocksum(const float* __restrict__ masks,
                                                  float* __restrict__ bs) {
  int gid = blockIdx.x;
  int yband = gid % 24;
  int bm = gid / 24;
  const float4* src = (const float4*)(masks + (I64)bm * (HMASK * WMASK) + (I64)yband * 16 * WMASK);
  int row = threadIdx.x / 24;
  int xb  = threadIdx.x % 24;
  const float4* p = src + row * 96 + xb * 4;
  float s = 0.f;
  #pragma unroll
  for (int j = 0; j < 4; ++j) {
    float4 v = p[j];
    s += v.x; s += v.y; s += v.z; s += v.w;
  }
  __shared__ float sm[16][24];
  sm[row][xb] = s;
  __syncthreads();
  if (threadIdx.x < 24) {
    float tt = 0.f;
    #pragma unroll
    for (int r = 0; r < 16; ++r) tt += sm[r][threadIdx.x];
    bs[(I64)bm * GNUM + yband * 24 + threadIdx.x] = tt;
  }
}

// ======================== K2: per-batch small ops ========================
__global__ __launch_bounds__(256) void k_perbatch(
    const float* __restrict__ bs, const float* __restrict__ scores,
    const float* __restrict__ W1, const float* __restrict__ b1,
    float* __restrict__ ws, float* __restrict__ out) {
  int b = blockIdx.x;
  int t = threadIdx.x;
  __shared__ float s_sc[NMASK];
  __shared__ int   s_order[NMASK];
  __shared__ float s_sck[KREG];
  __shared__ int   s_midx[KREG];
  __shared__ int   s_valid[KREG];
  __shared__ float s_rowsum[KREG];
  __shared__ float s_pp[GNUM];
  __shared__ float s_geom[KREG][5];
  __shared__ float s_red[64];
  __shared__ int   s_gv;
  __shared__ float s_ppsum;

  if (t == 0) s_gv = 0;
  __syncthreads();
  if (t < NMASK) {
    const float* p = bs + ((I64)b * NMASK + t) * GNUM;
    float s = 0.f;
    for (int n = 0; n < GNUM; ++n) s += p[n];
    if (s > 0.f) atomicOr(&s_gv, 1);
    s_sc[t] = scores[b * NMASK + t];
  }
  __syncthreads();
  const int gv = s_gv;
  if (t < NMASK) {
    float v = s_sc[t];
    int r = 0;
    for (int j = 0; j < NMASK; ++j) {
      float vj = s_sc[j];
      r += (vj > v) || (vj == v && j < t);
    }
    s_order[r] = t;
  }
  __syncthreads();
  if (t < KREG) {
    int m = s_order[t];
    float sc = s_sc[m];
    int valid = (sc >= 0.5f) ? 1 : 0;
    s_midx[t] = m;
    s_valid[t] = valid;
    float sck = gv ? (valid ? sc : 0.f) : 1.f;
    s_sck[t] = sck;
    ws[WS_SCK + b * KREG + t] = sck;
  }
  __syncthreads();

  const float inv256 = 1.f / 256.f;
  const float invN = 1.f / 576.f;
  auto MG = [&](int k, int n) -> float {
    if (!gv) return invN;
    if (!s_valid[k]) return 0.f;
    return bs[((I64)b * NMASK + s_midx[k]) * GNUM + n] * inv256;
  };

  {
    int k = t >> 3, sub = t & 7;
    float part = 0.f;
    for (int n = sub; n < GNUM; n += 8) part += fmaxf(MG(k, n), 0.f);
    part += __shfl_xor(part, 1);
    part += __shfl_xor(part, 2);
    part += __shfl_xor(part, 4);
    if (sub == 0) s_rowsum[k] = part;
  }
  __syncthreads();
  for (int idx = t; idx < KREG * GNUM; idx += 256) {
    int k = idx / GNUM, n = idx - k * GNUM;
    float v = fmaxf(MG(k, n), 0.f);
    ws[WS_NMAT + ((I64)b * KREG + k) * GNUM + n] = v / fmaxf(s_rowsum[k], 1e-6f);
  }
  for (int n = t; n < GNUM; n += 256) {
    float raw = 0.f;
    for (int k = 0; k < KREG; ++k) raw += MG(k, n) * s_sck[k];
    s_pp[n] = fmaxf(raw, 0.f);
  }
  __syncthreads();
  if (t < 64) {
    float s = 0.f;
    for (int n = t; n < GNUM; n += 64) s += s_pp[n];
    s_red[t] = s;
  }
  __syncthreads();
  if (t == 0) {
    float s = 0.f;
    for (int i = 0; i < 64; ++i) s += s_red[i];
    s_ppsum = s;
  }
  __syncthreads();
  {
    float den = fmaxf(s_ppsum, 1e-6f);
    for (int n = t; n < GNUM; n += 256) {
      float v = gv ? (s_pp[n] / den) : invN;
      ws[WS_PP + b * GNUM + n] = v;
      out[OFF_PP + b * GNUM + n] = v;
    }
  }
  if (t < KREG) {
    unsigned colmask = 0u;
    int ymin = GH, ymax = -1, cnt = 0;
    for (int y = 0; y < GH; ++y) {
      unsigned rowm = 0u;
      for (int x = 0; x < GW; ++x) {
        if (MG(t, y * GW + x) > 0.05f) rowm |= (1u << x);
      }
      if (rowm) { if (y < ymin) ymin = y; if (y > ymax) ymax = y; }
      colmask |= rowm;
      cnt += __popc(rowm);
    }
    float g0, g1, g2, g3, g4;
    if (cnt > 0) {
      int xmin = __ffs(colmask) - 1;
      int xmax = 31 - __clz(colmask);
      g0 = (float)xmin / 23.f;
      g1 = (float)ymin / 23.f;
      g2 = (float)xmax / 23.f;
      g3 = (float)ymax / 23.f;
      g4 = (float)cnt / 576.f;
    } else { g0 = g1 = g2 = g3 = g4 = 0.f; }
    s_geom[t][0] = g0; s_geom[t][1] = g1; s_geom[t][2] = g2; s_geom[t][3] = g3; s_geom[t][4] = g4;
  }
  __syncthreads();
  for (int idx = t; idx < KREG * HDIM; idx += 256) {
    int k = idx >> 10, j = idx & 1023;
    float x = 0.f;
    #pragma unroll
    for (int i = 0; i < 5; ++i) x += s_geom[k][i] * W1[i * HDIM + j];
    x += b1[j];
    float sg = 1.f / (1.f + expf(-x));
    ws[WS_H1 + ((I64)b * KREG + k) * HDIM + j] = x * sg;
  }
  if (t == 0) {
    float g = gv ? 1.f : 0.f;
    ws[WS_GV + b] = g;
    out[OFF_GV + b] = g;
  }
}

// ======================== K3: q = question_embed @ Wq + bq ========================
__global__ __launch_bounds__(256) void k_qrow(
    const float* __restrict__ qe, const float* __restrict__ Wq,
    const float* __restrict__ bq, float* __restrict__ ws) {
  int b = blockIdx.y;
  int dl = threadIdx.x & 15;
  int ig = threadIdx.x >> 4;
  int d = blockIdx.x * 16 + dl;
  float acc = 0.f;
  for (int i = ig; i < QDIM; i += 16)
    acc += qe[b * QDIM + i] * Wq[(I64)i * HDIM + d];
  __shared__ float s_part[16][16];
  s_part[ig][dl] = acc;
  __syncthreads();
  if (threadIdx.x < 16) {
    float s = 0.f;
    #pragma unroll
    for (int g = 0; g < 16; ++g) s += s_part[g][threadIdx.x];
    int dd = blockIdx.x * 16 + threadIdx.x;
    ws[WS_Q + (I64)b * HDIM + dd] = s + bq[dd];
  }
}

// ======================== K4: region tokens v2 ========================
// grid: 512 = 8b x 8kg(4 regions) x 8dg(128 cols), 256 threads = 128 d-lanes x 2 range-halves
__global__ __launch_bounds__(256) void k_region(
    const float* __restrict__ pt, const float* __restrict__ W2,
    const float* __restrict__ b2, const float* __restrict__ te,
    float* __restrict__ ws, float* __restrict__ out) {
  int blk = blockIdx.x;
  int b = blk >> 6, kg = (blk >> 3) & 7, dg = blk & 7;
  int t = threadIdx.x;
  int dl = t & 127;
  int th = t >> 7;
  int d = dg * 128 + dl;
  const float* nmb = ws + WS_NMAT + ((I64)b * KREG + kg * 4) * GNUM;
  const float* h1b = ws + WS_H1 + ((I64)b * KREG + kg * 4) * HDIM;
  float accP[4] = {0, 0, 0, 0};
  float accG[4] = {0, 0, 0, 0};
  int n0 = th * 288, n1 = n0 + 288;
  for (int n = n0; n < n1; ++n) {
    float p = pt[((I64)b * NTOK + n) * DIM + d];
    #pragma unroll
    for (int kk = 0; kk < 4; ++kk)
      accP[kk] = fmaf(nmb[kk * GNUM + n], p, accP[kk]);
  }
  int j0 = th * 512, j1 = j0 + 512;
  for (int j = j0; j < j1; ++j) {
    float wv = W2[(I64)j * DIM + d];
    #pragma unroll
    for (int kk = 0; kk < 4; ++kk)
      accG[kk] = fmaf(h1b[kk * HDIM + j], wv, accG[kk]);
  }
  __shared__ float cmbP[2][4][128];
  __shared__ float cmbG[2][4][128];
  #pragma unroll
  for (int kk = 0; kk < 4; ++kk) {
    cmbP[th][kk][dl] = accP[kk];
    cmbG[th][kk][dl] = accG[kk];
  }
  __syncthreads();
  if (th == 0) {
    float bb = b2[d], t0 = te[d];
    #pragma unroll
    for (int kk = 0; kk < 4; ++kk) {
      int k = kg * 4 + kk;
      float P = cmbP[0][kk][dl] + cmbP[1][kk][dl];
      float G = cmbG[0][kk][dl] + cmbG[1][kk][dl];
      float val = P * ws[WS_SCK + b * KREG + k] + G + bb + t0;
      out[OFF_REG + ((I64)b * KREG + k) * DIM + d] = val;
      out[OFF_VIS + ((I64)b * 161 + k) * DIM + d] = val;
    }
  }
}

// ======================== K5: fused hid GEMM v2 ========================
// C = pt(4608x1024) x Wv(1024x1024), epilogue tanh + Wo-dot -> partial scores.
// BM=48 tok, BN=128 col, BK=32. grid = 8b x 12 tokTile x 8 colTile = 768 (3/CU).
// 256 threads: tcol = t&31 (4 cols each), trow = t>>5 (6 tokens each). acc[6][4].
#define BM 48
#define BN 128
#define BK 32
#define KSTEPS (DIM / BK)
__global__ __launch_bounds__(256) void k_hid2(
    const float* __restrict__ pt, const float* __restrict__ Wv,
    const float* __restrict__ bv, const float* __restrict__ Wp,
    const float* __restrict__ bp, const float* __restrict__ Wo,
    float* __restrict__ ws) {
  int blk = blockIdx.x;
  int b  = blk / 96;
  int r  = blk % 96;
  int tt = r >> 3;          // 12 token tiles
  int ct = r & 7;           // 8 col tiles
  int n0 = tt * BM;
  int col0 = ct * BN;
  int t = threadIdx.x;
  int tcol = t & 31;
  int trow = t >> 5;

  __shared__ float sA[2][BK][BM];   // k-major: [kk][tok]
  __shared__ float sW[2][BK][BN];   // [kk][col]

  float acc[6][4];
  #pragma unroll
  for (int i = 0; i < 6; ++i)
    #pragma unroll
    for (int j = 0; j < 4; ++j) acc[i][j] = 0.f;

  // staging maps
  int a_tok = t >> 2, a_q = t & 3;                 // t<192: token, k-quarter
  const I64 a_row = ((I64)b * NTOK + n0 + a_tok) * DIM;
  int w_r = t >> 3, w_c = t & 7;                   // W: row (k), col-octant
  const float* w_base = Wv + (I64)w_r * HDIM + col0;

  float4 a0 = {0,0,0,0}, a1 = {0,0,0,0};
  float4 wr0, wr1, wr2, wr3;

  // prologue: load tile 0
  {
    if (t < 192) {
      a0 = *(const float4*)&pt[a_row + a_q * 8];
      a1 = *(const float4*)&pt[a_row + a_q * 8 + 4];
    }
    const float* wb = w_base;   // k0 = 0
    wr0 = *(const float4*)&wb[(w_c +  0) * 4];
    wr1 = *(const float4*)&wb[(w_c +  8) * 4];
    wr2 = *(const float4*)&wb[(w_c + 16) * 4];
    wr3 = *(const float4*)&wb[(w_c + 24) * 4];
    // write to buf 0
    if (t < 192) {
      #pragma unroll
      for (int j = 0; j < 4; ++j) {
        sA[0][a_q * 8 + j][a_tok]     = ((const float*)&a0)[j];
        sA[0][a_q * 8 + 4 + j][a_tok] = ((const float*)&a1)[j];
      }
    }
    *(float4*)&sW[0][w_r][(w_c +  0) * 4] = wr0;
    *(float4*)&sW[0][w_r][(w_c +  8) * 4] = wr1;
    *(float4*)&sW[0][w_r][(w_c + 16) * 4] = wr2;
    *(float4*)&sW[0][w_r][(w_c + 24) * 4] = wr3;
  }

  for (int s = 0; s < KSTEPS; ++s) {
    __syncthreads();
    int nb = s + 1;
    if (nb < KSTEPS) {
      int k0 = nb * BK;
      if (t < 192) {
        a0 = *(const float4*)&pt[a_row + k0 + a_q * 8];
        a1 = *(const float4*)&pt[a_row + k0 + a_q * 8 + 4];
      }
      const float* wb = w_base + (I64)k0 * HDIM;
      wr0 = *(const float4*)&wb[(w_c +  0) * 4];
      wr1 = *(const float4*)&wb[(w_c +  8) * 4];
      wr2 = *(const float4*)&wb[(w_c + 16) * 4];
      wr3 = *(const float4*)&wb[(w_c + 24) * 4];
    }
    int cur = s & 1;
    #pragma unroll 4
    for (int kk = 0; kk < BK; ++kk) {
      const float* ar = &sA[cur][kk][trow * 6];
      float2 a01 = *(const float2*)ar;
      float2 a23 = *(const float2*)(ar + 2);
      float2 a45 = *(const float2*)(ar + 4);
      float4 wv4 = *(const float4*)&sW[cur][kk][tcol * 4];
      float av[6] = {a01.x, a01.y, a23.x, a23.y, a45.x, a45.y};
      float wa[4] = {wv4.x, wv4.y, wv4.z, wv4.w};
      #pragma unroll
      for (int i = 0; i < 6; ++i)
        #pragma unroll
        for (int j = 0; j < 4; ++j)
          acc[i][j] = fmaf(av[i], wa[j], acc[i][j]);
    }
    if (nb < KSTEPS) {
      int nxt = nb & 1;
      if (t < 192) {
        #pragma unroll
        for (int j = 0; j < 4; ++j) {
          sA[nxt][a_q * 8 + j][a_tok]     = ((const float*)&a0)[j];
          sA[nxt][a_q * 8 + 4 + j][a_tok] = ((const float*)&a1)[j];
        }
      }
      *(float4*)&sW[nxt][w_r][(w_c +  0) * 4] = wr0;
      *(float4*)&sW[nxt][w_r][(w_c +  8) * 4] = wr1;
      *(float4*)&sW[nxt][w_r][(w_c + 16) * 4] = wr2;
      *(float4*)&sW[nxt][w_r][(w_c + 24) * 4] = wr3;
    }
  }

  // epilogue: tanh + Wo partial dot over this block's 128 cols
  int c = col0 + tcol * 4;
  float4 bv4 = *(const float4*)&bv[c];
  float4 bp4 = *(const float4*)&bp[c];
  float4 wp4 = *(const float4*)&Wp[c];
  float4 wo4 = *(const float4*)&Wo[c];
  float4 q4  = *(const float4*)&ws[WS_Q + (I64)b * HDIM + c];
  float bvv[4] = {bv4.x, bv4.y, bv4.z, bv4.w};
  float bpv[4] = {bp4.x, bp4.y, bp4.z, bp4.w};
  float wpv[4] = {wp4.x, wp4.y, wp4.z, wp4.w};
  float wov[4] = {wo4.x, wo4.y, wo4.z, wo4.w};
  float qv[4]  = {q4.x, q4.y, q4.z, q4.w};
  float partial[6];
  #pragma unroll
  for (int i = 0; i < 6; ++i) {
    float ppv = ws[WS_PP + b * GNUM + n0 + trow * 6 + i];
    float s = 0.f;
    #pragma unroll
    for (int j = 0; j < 4; ++j) {
      float pre = acc[i][j] + bvv[j] + bpv[j] + qv[j] + ppv * wpv[j];
      s = fmaf(wov[j], tanhf(pre), s);
    }
    partial[i] = s;
  }
  #pragma unroll
  for (int i = 0; i < 6; ++i) {
    float p = partial[i];
    p += __shfl_xor(p, 1);
    p += __shfl_xor(p, 2);
    p += __shfl_xor(p, 4);
    p += __shfl_xor(p, 8);
    p += __shfl_xor(p, 16);
    partial[i] = p;
  }
  if (tcol == 0) {
    #pragma unroll
    for (int i = 0; i < 6; ++i)
      ws[WS_RSP + ((I64)b * NTOK + n0 + trow * 6 + i) * 8 + ct] = partial[i];
  }
}

// ======================== K6: softmax + stable top-k ========================
__global__ __launch_bounds__(576) void k_soft(const float* __restrict__ bo,
                                              float* __restrict__ ws, float* __restrict__ out) {
  int b = blockIdx.x, t = threadIdx.x;
  __shared__ float s_rs[NTOK];
  __shared__ float s_w[9];
  __shared__ float s_max, s_sum;
  {
    const float* p = ws + WS_RSP + ((I64)b * NTOK + t) * 8;
    float s = bo[0];
    #pragma unroll
    for (int i = 0; i < 8; ++i) s += p[i];
    s_rs[t] = s;
  }
  __syncthreads();
  float v = s_rs[t];
  int r = 0;
  for (int j = 0; j < NTOK; ++j) {
    float vj = s_rs[j];
    r += (vj > v) || (vj == v && j < t);
  }
  float m = v;
  for (int off = 1; off < 64; off <<= 1) m = fmaxf(m, __shfl_xor(m, off));
  if ((t & 63) == 0) s_w[t >> 6] = m;
  __syncthreads();
  if (t == 0) {
    float mm = s_w[0];
    for (int i = 1; i < 9; ++i) mm = fmaxf(mm, s_w[i]);
    s_max = mm;
  }
  __syncthreads();
  float e = expf(v - s_max);
  float s = e;
  for (int off = 1; off < 64; off <<= 1) s += __shfl_xor(s, off);
  if ((t & 63) == 0) s_w[t >> 6] = s;
  __syncthreads();
  if (t == 0) {
    float ss = 0.f;
    for (int i = 0; i < 9; ++i) ss += s_w[i];
    s_sum = ss;
  }
  __syncthreads();
  out[OFF_RW + b * NTOK + t] = e / s_sum;
  int sel = (r < CCTX) ? 1 : 0;
  ws[WS_FLAG + b * NTOK + t] = sel ? 1.f : 0.f;
  if (sel) out[OFF_SEL + b * CCTX + r] = (float)t;
}

// ======================== K7: context gather ========================
__global__ __launch_bounds__(256) void k_ctx(const float* __restrict__ pt, const float* __restrict__ te,
                                             const float* __restrict__ outr, float* __restrict__ out) {
  int rr = blockIdx.x, b = blockIdx.y;
  int idx = (int)outr[OFF_SEL + b * CCTX + rr];
  int d = threadIdx.x * 4;
  float4 v = *(const float4*)&pt[((I64)b * NTOK + idx) * DIM + d];
  float4 e = *(const float4*)&te[DIM + d];
  v.x += e.x; v.y += e.y; v.z += e.z; v.w += e.w;
  *(float4*)&out[OFF_CTX + ((I64)b * CCTX + rr) * DIM + d] = v;
  *(float4*)&out[OFF_VIS + ((I64)b * 161 + KREG + rr) * DIM + d] = v;
}

// ======================== K8: background token ========================
__global__ __launch_bounds__(256) void k_bg(const float* __restrict__ pt, const float* __restrict__ te,
                                            const float* __restrict__ ws, float* __restrict__ out) {
  int b = blockIdx.x;
  int d = threadIdx.x * 4;
  const float r = 1.f / 448.f;
  float ax = 0.f, ay = 0.f, az = 0.f, aw = 0.f;
  for (int n = 0; n < NTOK; ++n) {
    if (ws[WS_FLAG + b * NTOK + n] == 0.f) {
      float4 v = *(const float4*)&pt[((I64)b * NTOK + n) * DIM + d];
      ax = fmaf(r, v.x, ax); ay = fmaf(r, v.y, ay);
      az = fmaf(r, v.z, az); aw = fmaf(r, v.w, aw);
    }
  }
  float4 e = *(const float4*)&te[2 * DIM + d];
  float4 o;
  o.x = ax + e.x; o.y = ay + e.y; o.z = az + e.z; o.w = aw + e.w;
  *(float4*)&out[OFF_BG + (I64)b * DIM + d] = o;
  *(float4*)&out[OFF_VIS + ((I64)b * 161 + 160) * DIM + d] = o;
}

// ======================== launcher ========================
extern "C" void kernel_launch(void* const* d_in, const int* in_sizes, int n_in,
                              void* d_out, int out_size, void* d_ws, size_t ws_size,
                              hipStream_t stream) {
  (void)in_sizes; (void)n_in; (void)out_size; (void)ws_size;
  const float* pt     = (const float*)d_in[0];
  const float* masks  = (const float*)d_in[1];
  const float* scores = (const float*)d_in[2];
  const float* qe     = (const float*)d_in[3];
  const float* W1     = (const float*)d_in[4];
  const float* b1     = (const float*)d_in[5];
  const float* W2     = (const float*)d_in[6];
  const float* b2     = (const float*)d_in[7];
  const float* Wv     = (const float*)d_in[8];
  const float* bv     = (const float*)d_in[9];
  const float* Wp     = (const float*)d_in[10];
  const float* bp     = (const float*)d_in[11];
  const float* Wq     = (const float*)d_in[12];
  const float* bq     = (const float*)d_in[13];
  const float* Wo     = (const float*)d_in[14];
  const float* bo     = (const float*)d_in[15];
  const float* te     = (const float*)d_in[16];
  float* out = (float*)d_out;
  float* ws  = (float*)d_ws;

  k_blocksum<<<dim3(NB * NMASK * 24), dim3(384), 0, stream>>>(masks, ws + WS_BS);
  k_perbatch<<<dim3(NB), dim3(256), 0, stream>>>(ws + WS_BS, scores, W1, b1, ws, out);
  k_qrow<<<dim3(HDIM / 16, NB), dim3(256), 0, stream>>>(qe, Wq, bq, ws);
  k_region<<<dim3(512), dim3(256), 0, stream>>>(pt, W2, b2, te, ws, out);
  k_hid2<<<dim3(768), dim3(256), 0, stream>>>(pt, Wv, bv, Wp, bp, Wo, ws);
  k_soft<<<dim3(NB), dim3(576), 0, stream>>>(bo, ws, out);
  k_ctx<<<dim3(CCTX, NB), dim3(256), 0, stream>>>(pt, te, out, out);
  k_bg<<<dim3(NB), dim3(256), 0, stream>>>(pt, te, ws, out);
}

// Round 3
// 429.514 us; speedup vs baseline: 2.3693x; 1.6331x over previous
//
#include <hip/hip_runtime.h>
#include <math.h>

typedef long long I64;

// ---- problem constants ----
#define NB    8
#define NTOK  576
#define DIM   1024
#define NMASK 64
#define HMASK 384
#define WMASK 384
#define QDIM  4096
#define HDIM  1024
#define KREG  32
#define CCTX  128
#define GH    24
#define GW    24
#define GNUM  576

// ---- output layout (floats) ----
#define OFF_VIS 0
#define OFF_REG 1318912
#define OFF_CTX 1581056
#define OFF_BG  2629632
#define OFF_PP  2637824
#define OFF_RW  2642432
#define OFF_SEL 2647040
#define OFF_GV  2648064

// ---- workspace layout (floats) ----
#define WS_BS   0          // B*M*576 block sums
#define WS_NMAT 294912     // B*32*576 normalized masks
#define WS_SCK  442368     // B*32 scores_k
#define WS_H1   442624     // B*32*1024 silu hidden
#define WS_Q    704768     // B*1024 question row
#define WS_RS   712960     // B*576 routing scores
#define WS_GV   717568     // B grounding_valid
#define WS_FLAG 717576     // B*576 selected flag (unused now)
#define WS_PP   722184     // B*576 patch prior
#define WS_RSP  726792     // B*576*8 routing score partials
#define WS_CS   763656     // B*1024 token colsum
// total 771848 floats ~ 3.09 MB

// ======================== K1: mask 16x16 block sums ========================
__global__ __launch_bounds__(384) void k_blocksum(const float* __restrict__ masks,
                                                  float* __restrict__ bs) {
  int gid = blockIdx.x;
  int yband = gid % 24;
  int bm = gid / 24;
  const float4* src = (const float4*)(masks + (I64)bm * (HMASK * WMASK) + (I64)yband * 16 * WMASK);
  int row = threadIdx.x / 24;
  int xb  = threadIdx.x % 24;
  const float4* p = src + row * 96 + xb * 4;
  float s = 0.f;
  #pragma unroll
  for (int j = 0; j < 4; ++j) {
    float4 v = p[j];
    s += v.x; s += v.y; s += v.z; s += v.w;
  }
  __shared__ float sm[16][24];
  sm[row][xb] = s;
  __syncthreads();
  if (threadIdx.x < 24) {
    float tt = 0.f;
    #pragma unroll
    for (int r = 0; r < 16; ++r) tt += sm[r][threadIdx.x];
    bs[(I64)bm * GNUM + yband * 24 + threadIdx.x] = tt;
  }
}

// ======================== K2: per-batch small ops (LDS-staged) ========================
#define MGPAD 580
__global__ __launch_bounds__(256) void k_perbatch(
    const float* __restrict__ bs, const float* __restrict__ scores,
    const float* __restrict__ W1, const float* __restrict__ b1,
    float* __restrict__ ws, float* __restrict__ out) {
  int b = blockIdx.x;
  int t = threadIdx.x;
  __shared__ float s_mg[KREG][MGPAD];
  __shared__ float s_sc[NMASK];
  __shared__ float s_msum[NMASK];
  __shared__ int   s_order[NMASK];
  __shared__ float s_sck[KREG];
  __shared__ int   s_valid[KREG];
  __shared__ int   s_midx[KREG];
  __shared__ float s_rowsum[KREG];
  __shared__ float s_pp[GNUM];
  __shared__ float s_geom[KREG][5];
  __shared__ float s_red[64];
  __shared__ int   s_gv;
  __shared__ float s_ppsum;

  // mask totals for all 64 masks: 4 threads per mask, coalesced float4
  {
    int m = t >> 2, q = t & 3;
    const float4* p = (const float4*)(bs + ((I64)b * NMASK + m) * GNUM) + q * 36;
    float s = 0.f;
    #pragma unroll 4
    for (int j = 0; j < 36; ++j) {
      float4 v = p[j];
      s += v.x; s += v.y; s += v.z; s += v.w;
    }
    s += __shfl_xor(s, 1);
    s += __shfl_xor(s, 2);
    if (q == 0) s_msum[m] = s;
  }
  if (t < NMASK) s_sc[t] = scores[b * NMASK + t];
  __syncthreads();
  if (t == 0) {
    int g = 0;
    for (int m = 0; m < NMASK; ++m) g |= (s_msum[m] > 0.f) ? 1 : 0;
    s_gv = g;
  }
  // stable descending rank
  if (t < NMASK) {
    float v = s_sc[t];
    int r = 0;
    for (int j = 0; j < NMASK; ++j) {
      float vj = s_sc[j];
      r += (vj > v) || (vj == v && j < t);
    }
    s_order[r] = t;
  }
  __syncthreads();
  const int gv = s_gv;
  if (t < KREG) {
    int m = s_order[t];
    float sc = s_sc[m];
    int valid = (sc >= 0.5f) ? 1 : 0;
    s_midx[t] = m;
    s_valid[t] = valid;
    float sck = gv ? (valid ? sc : 0.f) : 1.f;
    s_sck[t] = sck;
    ws[WS_SCK + b * KREG + t] = sck;
  }
  __syncthreads();
  // stage mg into LDS: mg = gv ? (valid ? bs/256 : 0) : 1/N
  {
    int k = t >> 3, sub = t & 7;
    const float inv256 = 1.f / 256.f;
    const float invN = 1.f / 576.f;
    float scale = gv ? (s_valid[k] ? inv256 : 0.f) : 0.f;
    float addv  = gv ? 0.f : invN;
    const float4* src = (const float4*)(bs + ((I64)b * NMASK + s_midx[k]) * GNUM) + sub * 18;
    float* dst = &s_mg[k][sub * 72];
    #pragma unroll 3
    for (int j = 0; j < 18; ++j) {
      float4 v = src[j];
      v.x = v.x * scale + addv;
      v.y = v.y * scale + addv;
      v.z = v.z * scale + addv;
      v.w = v.w * scale + addv;
      *(float4*)(dst + j * 4) = v;
    }
  }
  __syncthreads();
  // row sums
  {
    int k = t >> 3, sub = t & 7;
    float part = 0.f;
    for (int n = sub; n < GNUM; n += 8) part += fmaxf(s_mg[k][n], 0.f);
    part += __shfl_xor(part, 1);
    part += __shfl_xor(part, 2);
    part += __shfl_xor(part, 4);
    if (sub == 0) s_rowsum[k] = part;
  }
  __syncthreads();
  // nm = max(mg,0)/max(rowsum,1e-6) -> ws
  for (int idx = t; idx < KREG * GNUM; idx += 256) {
    int k = idx / GNUM, n = idx - k * GNUM;
    float v = fmaxf(s_mg[k][n], 0.f);
    ws[WS_NMAT + ((I64)b * KREG + k) * GNUM + n] = v / fmaxf(s_rowsum[k], 1e-6f);
  }
  // patch prior raw
  for (int n = t; n < GNUM; n += 256) {
    float raw = 0.f;
    #pragma unroll
    for (int k = 0; k < KREG; ++k) raw = fmaf(s_mg[k][n], s_sck[k], raw);
    s_pp[n] = fmaxf(raw, 0.f);
  }
  __syncthreads();
  if (t < 64) {
    float s = 0.f;
    for (int n = t; n < GNUM; n += 64) s += s_pp[n];
    s_red[t] = s;
  }
  __syncthreads();
  if (t == 0) {
    float s = 0.f;
    for (int i = 0; i < 64; ++i) s += s_red[i];
    s_ppsum = s;
  }
  __syncthreads();
  {
    const float invN = 1.f / 576.f;
    float den = fmaxf(s_ppsum, 1e-6f);
    for (int n = t; n < GNUM; n += 256) {
      float v = gv ? (s_pp[n] / den) : invN;
      ws[WS_PP + b * GNUM + n] = v;
      out[OFF_PP + b * GNUM + n] = v;
    }
  }
  // geometry: 8 threads per region, 3 y-rows each, shfl combine
  {
    int k = t >> 3, sub = t & 7;
    unsigned colmask = 0u;
    int ymin = GH, ymax = -1, cnt = 0;
    #pragma unroll
    for (int yy = 0; yy < 3; ++yy) {
      int y = sub * 3 + yy;
      unsigned rowm = 0u;
      for (int x = 0; x < GW; ++x)
        if (s_mg[k][y * GW + x] > 0.05f) rowm |= (1u << x);
      if (rowm) { if (y < ymin) ymin = y; if (y > ymax) ymax = y; }
      colmask |= rowm;
      cnt += __popc(rowm);
    }
    #pragma unroll
    for (int off = 1; off < 8; off <<= 1) {
      colmask |= (unsigned)__shfl_xor((int)colmask, off);
      cnt += __shfl_xor(cnt, off);
      int o1 = __shfl_xor(ymin, off); ymin = (o1 < ymin) ? o1 : ymin;
      int o2 = __shfl_xor(ymax, off); ymax = (o2 > ymax) ? o2 : ymax;
    }
    if (sub == 0) {
      float g0, g1, g2, g3, g4;
      if (cnt > 0) {
        int xmin = __ffs(colmask) - 1;
        int xmax = 31 - __clz(colmask);
        g0 = (float)xmin / 23.f;
        g1 = (float)ymin / 23.f;
        g2 = (float)xmax / 23.f;
        g3 = (float)ymax / 23.f;
        g4 = (float)cnt / 576.f;
      } else { g0 = g1 = g2 = g3 = g4 = 0.f; }
      s_geom[k][0] = g0; s_geom[k][1] = g1; s_geom[k][2] = g2;
      s_geom[k][3] = g3; s_geom[k][4] = g4;
    }
  }
  __syncthreads();
  // hidden1 = silu(geom @ W1 + b1)
  for (int idx = t; idx < KREG * HDIM; idx += 256) {
    int k = idx >> 10, j = idx & 1023;
    float x = 0.f;
    #pragma unroll
    for (int i = 0; i < 5; ++i) x += s_geom[k][i] * W1[i * HDIM + j];
    x += b1[j];
    float sg = 1.f / (1.f + expf(-x));
    ws[WS_H1 + ((I64)b * KREG + k) * HDIM + j] = x * sg;
  }
  if (t == 0) {
    float g = gv ? 1.f : 0.f;
    ws[WS_GV + b] = g;
    out[OFF_GV + b] = g;
  }
}

// ======================== K3: q = question_embed @ Wq + bq ========================
__global__ __launch_bounds__(256) void k_qrow(
    const float* __restrict__ qe, const float* __restrict__ Wq,
    const float* __restrict__ bq, float* __restrict__ ws) {
  int b = blockIdx.y;
  int dl = threadIdx.x & 15;
  int ig = threadIdx.x >> 4;
  int d = blockIdx.x * 16 + dl;
  float acc = 0.f;
  for (int i = ig; i < QDIM; i += 16)
    acc += qe[b * QDIM + i] * Wq[(I64)i * HDIM + d];
  __shared__ float s_part[16][16];
  s_part[ig][dl] = acc;
  __syncthreads();
  if (threadIdx.x < 16) {
    float s = 0.f;
    #pragma unroll
    for (int g = 0; g < 16; ++g) s += s_part[g][threadIdx.x];
    int dd = blockIdx.x * 16 + threadIdx.x;
    ws[WS_Q + (I64)b * HDIM + dd] = s + bq[dd];
  }
}

// ======================== K4: region tokens + colsum ========================
// grid: 512 = 8b x 8kg(4 regions) x 8dg(128 cols), 256 threads = 128 d-lanes x 2 halves
__global__ __launch_bounds__(256) void k_region(
    const float* __restrict__ pt, const float* __restrict__ W2,
    const float* __restrict__ b2, const float* __restrict__ te,
    float* __restrict__ ws, float* __restrict__ out) {
  int blk = blockIdx.x;
  int b = blk >> 6, kg = (blk >> 3) & 7, dg = blk & 7;
  int t = threadIdx.x;
  int dl = t & 127;
  int th = t >> 7;
  int d = dg * 128 + dl;
  const float* nmb = ws + WS_NMAT + ((I64)b * KREG + kg * 4) * GNUM;
  const float* h1b = ws + WS_H1 + ((I64)b * KREG + kg * 4) * HDIM;
  float accP[4] = {0, 0, 0, 0};
  float accG[4] = {0, 0, 0, 0};
  float accS = 0.f;
  int n0 = th * 288, n1 = n0 + 288;
  for (int n = n0; n < n1; ++n) {
    float p = pt[((I64)b * NTOK + n) * DIM + d];
    accS += p;
    #pragma unroll
    for (int kk = 0; kk < 4; ++kk)
      accP[kk] = fmaf(nmb[kk * GNUM + n], p, accP[kk]);
  }
  int j0 = th * 512, j1 = j0 + 512;
  for (int j = j0; j < j1; ++j) {
    float wv = W2[(I64)j * DIM + d];
    #pragma unroll
    for (int kk = 0; kk < 4; ++kk)
      accG[kk] = fmaf(h1b[kk * HDIM + j], wv, accG[kk]);
  }
  __shared__ float cmbP[2][4][128];
  __shared__ float cmbG[2][4][128];
  __shared__ float cmbS[2][128];
  #pragma unroll
  for (int kk = 0; kk < 4; ++kk) {
    cmbP[th][kk][dl] = accP[kk];
    cmbG[th][kk][dl] = accG[kk];
  }
  cmbS[th][dl] = accS;
  __syncthreads();
  if (th == 0) {
    float bb = b2[d], t0 = te[d];
    #pragma unroll
    for (int kk = 0; kk < 4; ++kk) {
      int k = kg * 4 + kk;
      float P = cmbP[0][kk][dl] + cmbP[1][kk][dl];
      float G = cmbG[0][kk][dl] + cmbG[1][kk][dl];
      float val = P * ws[WS_SCK + b * KREG + k] + G + bb + t0;
      out[OFF_REG + ((I64)b * KREG + k) * DIM + d] = val;
      out[OFF_VIS + ((I64)b * 161 + k) * DIM + d] = val;
    }
    if (kg == 0)
      ws[WS_CS + (I64)b * DIM + d] = cmbS[0][dl] + cmbS[1][dl];
  }
}

// ======================== K5: fused hid GEMM ========================
#define BM 48
#define BN 128
#define BK 32
#define KSTEPS (DIM / BK)
__global__ __launch_bounds__(256) void k_hid2(
    const float* __restrict__ pt, const float* __restrict__ Wv,
    const float* __restrict__ bv, const float* __restrict__ Wp,
    const float* __restrict__ bp, const float* __restrict__ Wo,
    float* __restrict__ ws) {
  int blk = blockIdx.x;
  int b  = blk / 96;
  int r  = blk % 96;
  int tt = r >> 3;
  int ct = r & 7;
  int n0 = tt * BM;
  int col0 = ct * BN;
  int t = threadIdx.x;
  int tcol = t & 31;
  int trow = t >> 5;

  __shared__ float sA[2][BK][BM];
  __shared__ float sW[2][BK][BN];

  float acc[6][4];
  #pragma unroll
  for (int i = 0; i < 6; ++i)
    #pragma unroll
    for (int j = 0; j < 4; ++j) acc[i][j] = 0.f;

  int a_tok = t >> 2, a_q = t & 3;
  const I64 a_row = ((I64)b * NTOK + n0 + a_tok) * DIM;
  int w_r = t >> 3, w_c = t & 7;
  const float* w_base = Wv + (I64)w_r * HDIM + col0;

  float4 a0 = {0,0,0,0}, a1 = {0,0,0,0};
  float4 wr0, wr1, wr2, wr3;

  {
    if (t < 192) {
      a0 = *(const float4*)&pt[a_row + a_q * 8];
      a1 = *(const float4*)&pt[a_row + a_q * 8 + 4];
    }
    const float* wb = w_base;
    wr0 = *(const float4*)&wb[(w_c +  0) * 4];
    wr1 = *(const float4*)&wb[(w_c +  8) * 4];
    wr2 = *(const float4*)&wb[(w_c + 16) * 4];
    wr3 = *(const float4*)&wb[(w_c + 24) * 4];
    if (t < 192) {
      #pragma unroll
      for (int j = 0; j < 4; ++j) {
        sA[0][a_q * 8 + j][a_tok]     = ((const float*)&a0)[j];
        sA[0][a_q * 8 + 4 + j][a_tok] = ((const float*)&a1)[j];
      }
    }
    *(float4*)&sW[0][w_r][(w_c +  0) * 4] = wr0;
    *(float4*)&sW[0][w_r][(w_c +  8) * 4] = wr1;
    *(float4*)&sW[0][w_r][(w_c + 16) * 4] = wr2;
    *(float4*)&sW[0][w_r][(w_c + 24) * 4] = wr3;
  }

  for (int s = 0; s < KSTEPS; ++s) {
    __syncthreads();
    int nb = s + 1;
    if (nb < KSTEPS) {
      int k0 = nb * BK;
      if (t < 192) {
        a0 = *(const float4*)&pt[a_row + k0 + a_q * 8];
        a1 = *(const float4*)&pt[a_row + k0 + a_q * 8 + 4];
      }
      const float* wb = w_base + (I64)k0 * HDIM;
      wr0 = *(const float4*)&wb[(w_c +  0) * 4];
      wr1 = *(const float4*)&wb[(w_c +  8) * 4];
      wr2 = *(const float4*)&wb[(w_c + 16) * 4];
      wr3 = *(const float4*)&wb[(w_c + 24) * 4];
    }
    int cur = s & 1;
    #pragma unroll 4
    for (int kk = 0; kk < BK; ++kk) {
      const float* ar = &sA[cur][kk][trow * 6];
      float2 a01 = *(const float2*)ar;
      float2 a23 = *(const float2*)(ar + 2);
      float2 a45 = *(const float2*)(ar + 4);
      float4 wv4 = *(const float4*)&sW[cur][kk][tcol * 4];
      float av[6] = {a01.x, a01.y, a23.x, a23.y, a45.x, a45.y};
      float wa[4] = {wv4.x, wv4.y, wv4.z, wv4.w};
      #pragma unroll
      for (int i = 0; i < 6; ++i)
        #pragma unroll
        for (int j = 0; j < 4; ++j)
          acc[i][j] = fmaf(av[i], wa[j], acc[i][j]);
    }
    if (nb < KSTEPS) {
      int nxt = nb & 1;
      if (t < 192) {
        #pragma unroll
        for (int j = 0; j < 4; ++j) {
          sA[nxt][a_q * 8 + j][a_tok]     = ((const float*)&a0)[j];
          sA[nxt][a_q * 8 + 4 + j][a_tok] = ((const float*)&a1)[j];
        }
      }
      *(float4*)&sW[nxt][w_r][(w_c +  0) * 4] = wr0;
      *(float4*)&sW[nxt][w_r][(w_c +  8) * 4] = wr1;
      *(float4*)&sW[nxt][w_r][(w_c + 16) * 4] = wr2;
      *(float4*)&sW[nxt][w_r][(w_c + 24) * 4] = wr3;
    }
  }

  int c = col0 + tcol * 4;
  float4 bv4 = *(const float4*)&bv[c];
  float4 bp4 = *(const float4*)&bp[c];
  float4 wp4 = *(const float4*)&Wp[c];
  float4 wo4 = *(const float4*)&Wo[c];
  float4 q4  = *(const float4*)&ws[WS_Q + (I64)b * HDIM + c];
  float bvv[4] = {bv4.x, bv4.y, bv4.z, bv4.w};
  float bpv[4] = {bp4.x, bp4.y, bp4.z, bp4.w};
  float wpv[4] = {wp4.x, wp4.y, wp4.z, wp4.w};
  float wov[4] = {wo4.x, wo4.y, wo4.z, wo4.w};
  float qv[4]  = {q4.x, q4.y, q4.z, q4.w};
  float partial[6];
  #pragma unroll
  for (int i = 0; i < 6; ++i) {
    float ppv = ws[WS_PP + b * GNUM + n0 + trow * 6 + i];
    float s = 0.f;
    #pragma unroll
    for (int j = 0; j < 4; ++j) {
      float pre = acc[i][j] + bvv[j] + bpv[j] + qv[j] + ppv * wpv[j];
      s = fmaf(wov[j], tanhf(pre), s);
    }
    partial[i] = s;
  }
  #pragma unroll
  for (int i = 0; i < 6; ++i) {
    float p = partial[i];
    p += __shfl_xor(p, 1);
    p += __shfl_xor(p, 2);
    p += __shfl_xor(p, 4);
    p += __shfl_xor(p, 8);
    p += __shfl_xor(p, 16);
    partial[i] = p;
  }
  if (tcol == 0) {
    #pragma unroll
    for (int i = 0; i < 6; ++i)
      ws[WS_RSP + ((I64)b * NTOK + n0 + trow * 6 + i) * 8 + ct] = partial[i];
  }
}

// ======================== K6: softmax + stable top-k ========================
__global__ __launch_bounds__(576) void k_soft(const float* __restrict__ bo,
                                              float* __restrict__ ws, float* __restrict__ out) {
  int b = blockIdx.x, t = threadIdx.x;
  __shared__ float s_rs[NTOK];
  __shared__ float s_w[9];
  __shared__ float s_max, s_sum;
  {
    const float* p = ws + WS_RSP + ((I64)b * NTOK + t) * 8;
    float s = bo[0];
    #pragma unroll
    for (int i = 0; i < 8; ++i) s += p[i];
    s_rs[t] = s;
  }
  __syncthreads();
  float v = s_rs[t];
  int r = 0;
  for (int j = 0; j < NTOK; ++j) {
    float vj = s_rs[j];
    r += (vj > v) || (vj == v && j < t);
  }
  float m = v;
  for (int off = 1; off < 64; off <<= 1) m = fmaxf(m, __shfl_xor(m, off));
  if ((t & 63) == 0) s_w[t >> 6] = m;
  __syncthreads();
  if (t == 0) {
    float mm = s_w[0];
    for (int i = 1; i < 9; ++i) mm = fmaxf(mm, s_w[i]);
    s_max = mm;
  }
  __syncthreads();
  float e = expf(v - s_max);
  float s = e;
  for (int off = 1; off < 64; off <<= 1) s += __shfl_xor(s, off);
  if ((t & 63) == 0) s_w[t >> 6] = s;
  __syncthreads();
  if (t == 0) {
    float ss = 0.f;
    for (int i = 0; i < 9; ++i) ss += s_w[i];
    s_sum = ss;
  }
  __syncthreads();
  out[OFF_RW + b * NTOK + t] = e / s_sum;
  if (r < CCTX) out[OFF_SEL + b * CCTX + r] = (float)t;
}

// ======================== K7: context gather ========================
__global__ __launch_bounds__(256) void k_ctx(const float* __restrict__ pt, const float* __restrict__ te,
                                             const float* __restrict__ outr, float* __restrict__ out) {
  int rr = blockIdx.x, b = blockIdx.y;
  int idx = (int)outr[OFF_SEL + b * CCTX + rr];
  int d = threadIdx.x * 4;
  float4 v = *(const float4*)&pt[((I64)b * NTOK + idx) * DIM + d];
  float4 e = *(const float4*)&te[DIM + d];
  v.x += e.x; v.y += e.y; v.z += e.z; v.w += e.w;
  *(float4*)&out[OFF_CTX + ((I64)b * CCTX + rr) * DIM + d] = v;
  *(float4*)&out[OFF_VIS + ((I64)b * 161 + KREG + rr) * DIM + d] = v;
}

// ======================== K8: background = (colsum - sum(selected)) / 448 ========================
__global__ __launch_bounds__(256) void k_bg(const float* __restrict__ pt, const float* __restrict__ te,
                                            const float* __restrict__ ws, const float* __restrict__ outr,
                                            float* __restrict__ out) {
  int b = blockIdx.x;
  int d = threadIdx.x * 4;
  float4 s = *(const float4*)&ws[WS_CS + (I64)b * DIM + d];
  for (int r = 0; r < CCTX; ++r) {
    int idx = (int)outr[OFF_SEL + b * CCTX + r];
    float4 v = *(const float4*)&pt[((I64)b * NTOK + idx) * DIM + d];
    s.x -= v.x; s.y -= v.y; s.z -= v.z; s.w -= v.w;
  }
  const float rinv = 1.f / 448.f;
  float4 e = *(const float4*)&te[2 * DIM + d];
  float4 o;
  o.x = s.x * rinv + e.x; o.y = s.y * rinv + e.y;
  o.z = s.z * rinv + e.z; o.w = s.w * rinv + e.w;
  *(float4*)&out[OFF_BG + (I64)b * DIM + d] = o;
  *(float4*)&out[OFF_VIS + ((I64)b * 161 + 160) * DIM + d] = o;
}

// ======================== launcher ========================
extern "C" void kernel_launch(void* const* d_in, const int* in_sizes, int n_in,
                              void* d_out, int out_size, void* d_ws, size_t ws_size,
                              hipStream_t stream) {
  (void)in_sizes; (void)n_in; (void)out_size; (void)ws_size;
  const float* pt     = (const float*)d_in[0];
  const float* masks  = (const float*)d_in[1];
  const float* scores = (const float*)d_in[2];
  const float* qe     = (const float*)d_in[3];
  const float* W1     = (const float*)d_in[4];
  const float* b1     = (const float*)d_in[5];
  const float* W2     = (const float*)d_in[6];
  const float* b2     = (const float*)d_in[7];
  const float* Wv     = (const float*)d_in[8];
  const float* bv     = (const float*)d_in[9];
  const float* Wp     = (const float*)d_in[10];
  const float* bp     = (const float*)d_in[11];
  const float* Wq     = (const float*)d_in[12];
  const float* bq     = (const float*)d_in[13];
  const float* Wo     = (const float*)d_in[14];
  const float* bo     = (const float*)d_in[15];
  const float* te     = (const float*)d_in[16];
  float* out = (float*)d_out;
  float* ws  = (float*)d_ws;

  k_blocksum<<<dim3(NB * NMASK * 24), dim3(384), 0, stream>>>(masks, ws + WS_BS);
  k_perbatch<<<dim3(NB), dim3(256), 0, stream>>>(ws + WS_BS, scores, W1, b1, ws, out);
  k_qrow<<<dim3(HDIM / 16, NB), dim3(256), 0, stream>>>(qe, Wq, bq, ws);
  k_region<<<dim3(512), dim3(256), 0, stream>>>(pt, W2, b2, te, ws, out);
  k_hid2<<<dim3(768), dim3(256), 0, stream>>>(pt, Wv, bv, Wp, bp, Wo, ws);
  k_soft<<<dim3(NB), dim3(576), 0, stream>>>(bo, ws, out);
  k_ctx<<<dim3(CCTX, NB), dim3(256), 0, stream>>>(pt, te, out, out);
  k_bg<<<dim3(NB), dim3(256), 0, stream>>>(pt, te, ws, out, out);
}